// Round 15
// baseline (1447.962 us; speedup 1.0000x reference)
//
#include <hip/hip_runtime.h>
#include <hip/hip_bf16.h>

typedef __attribute__((ext_vector_type(4))) float  f32x4;
typedef __attribute__((ext_vector_type(4))) int    i32x4;
typedef __attribute__((ext_vector_type(8))) int    i32x8;

// problem constants
#define NOBJ 2048
#define NREL 16384
#define DIM  1024
#define KOBJ 34816   /* 16384 + 16384 + 2048 */
#define KREL 4096    /* 2048 + 2048 */
#define EPS  1e-7f

#define AS1Q __attribute__((address_space(1)))
#define AS3Q __attribute__((address_space(3)))

__device__ __forceinline__ void gload_lds16(const void* g, void* l) {
    __builtin_amdgcn_global_load_lds((AS1Q void*)const_cast<void*>(g),
                                     (AS3Q void*)l, 16, 0, 0);
}

// all-ones (E8M0 = 127) block scales: plain fp8 matmul at MX rate
#define MFMA_F8(ACC, Af, Bf) \
    ACC = __builtin_amdgcn_mfma_scale_f32_16x16x128_f8f6f4( \
        Af, Bf, ACC, 0, 0, 0, 0x7F7F7F7F, 0, 0x7F7F7F7F)

__device__ __forceinline__ unsigned char fp8_byte(float x) {
    return (unsigned char)(__builtin_amdgcn_cvt_pk_fp8_f32(x, x, 0, false) & 0xFF);
}
__device__ __forceinline__ unsigned pk4_fp8(float a, float b, float c, float d) {
    int v = __builtin_amdgcn_cvt_pk_fp8_f32(a, b, 0, false);
    v = __builtin_amdgcn_cvt_pk_fp8_f32(c, d, v, true);
    return (unsigned)v;
}

// ---------------------------------------------------------------------------
// Merged MX-fp8 FC kernel (fc01 + f234 in one dispatch), occ structure.
// (unchanged from R14)
// ---------------------------------------------------------------------------
__global__ __launch_bounds__(512, 4)
void gemmf8mlp(const unsigned char* __restrict__ W01, const unsigned char* __restrict__ xrel8,
               const unsigned char* __restrict__ W234, const unsigned char* __restrict__ xobj8,
               const float* __restrict__ b01, const float* __restrict__ bstk,
               unsigned char* __restrict__ fcObj8, unsigned char* __restrict__ fcRel8)
{
    __shared__ __align__(16) char lds[49152];

    const int tid  = threadIdx.x;
    const int lane = tid & 63;
    const int wid  = tid >> 6;
    const int wr = wid >> 2, wc = wid & 3;
    const int l15 = lane & 15, lk = lane >> 4;

    const int bid = blockIdx.x;                 // 1216, %8==0
    const int s   = (bid & 7) * 152 + (bid >> 3);

    const unsigned char* A; const unsigned char* B; const float* bias; bool isFC;
    long rowM0, rowN0;
    if (s < 1024) {
        rowM0 = (long)(s >> 6) * 128;
        rowN0 = (long)(s & 63) * 256;
        A = W01; B = xrel8; bias = b01; isFC = true;
    } else {
        const int t = s - 1024;
        rowM0 = (long)(t >> 3) * 128;
        rowN0 = (long)(t & 7) * 256;
        A = W234; B = xobj8; bias = bstk; isFC = false;
    }
    const long ld = DIM;
    const int  NT = DIM >> 7;           // 8

    const int rs = tid >> 3;
    const int kc = (tid & 7) ^ (rs & 7);
    const char* gA = (const char*)A + (rowM0 + rs) * ld + kc * 16;
    const char* gB = (const char*)B + (rowN0 + rs) * ld + kc * 16;
    char* lA = (char*)lds + tid * 16;
    char* lB = (char*)lds + 16384 + tid * 16;

    const int xc0 = ((2 * lk + 0) ^ (l15 & 7)) * 16;
    const int xc1 = ((2 * lk + 1) ^ (l15 & 7)) * 16;
    const int baseA = (wr * 64 + l15) * 128;
    const int baseB = 16384 + (wc * 64 + l15) * 128;

#define LDF8(dst, off) { \
    i32x4 lo_ = *(const i32x4*)((const char*)lds + (off) + xc0); \
    i32x4 hi_ = *(const i32x4*)((const char*)lds + (off) + xc1); \
    dst = __builtin_shufflevector(lo_, hi_, 0, 1, 2, 3, 4, 5, 6, 7); }

    f32x4 acc[4][4];
    #pragma unroll
    for (int i = 0; i < 4; i++)
        #pragma unroll
        for (int j = 0; j < 4; j++) acc[i][j] = f32x4{0.f, 0.f, 0.f, 0.f};

    for (int t = 0; t < NT; ++t) {
        const long kByte = (long)t * 128;
        gload_lds16(gA + kByte, lA);
        gload_lds16(gA + kByte + 64 * ld, lA + 8192);
        #pragma unroll
        for (int i = 0; i < 4; i++)
            gload_lds16(gB + kByte + (long)i * 64 * ld, lB + i * 8192);
        __syncthreads();

        i32x8 a[4];
        #pragma unroll
        for (int kf = 0; kf < 4; kf++) LDF8(a[kf], baseA + kf * 2048);
        #pragma unroll
        for (int j = 0; j < 4; j++) {
            i32x8 b;
            LDF8(b, baseB + j * 2048);
            #pragma unroll
            for (int kf = 0; kf < 4; kf++) MFMA_F8(acc[kf][j], a[kf], b);
        }
        __syncthreads();
    }
#undef LDF8

    #pragma unroll
    for (int kf = 0; kf < 4; kf++) {
        const long m0 = rowM0 + wr * 64 + kf * 16 + lk * 4;
        #pragma unroll
        for (int r = 0; r < 4; r++) {
            const long m = m0 + r;
            const float bs = 64.f * bias[m];
            #pragma unroll
            for (int j = 0; j < 4; j++) {
                const long n = rowN0 + wc * 64 + j * 16 + l15;
                const float v = fmaxf(acc[kf][j][r] + bs, 0.f);
                const unsigned char o = fp8_byte(v);
                if (isFC) {
                    fcObj8[(m & 1023) * (long)KOBJ + (m >> 10) * 16384 + n] = o;
                } else {
                    if (m < 1024)       fcRel8[m * (long)KREL + n] = o;
                    else if (m < 2048)  fcRel8[(m - 1024) * (long)KREL + 2048 + n] = o;
                    else                fcObj8[(m - 2048) * (long)KOBJ + 32768 + n] = o;
                }
            }
        }
    }
}

// ---------------------------------------------------------------------------
// Dual-role 128x256 MX-fp8 collect kernel. Attn operands carry FIXED x16
// scale; per-segment row scales applied via in-place acc ratio rescale at
// K segment boundaries + per-row final scale in the epilogue.
//   colObj K segments: AS [0,128) | AO [128,256) | ASelf [256,272) tiles
//     ratios rat1 = s1/s2, rat2 = s2/s3; final finO[m] = s3/(3*1024)
//   colRel K segments: AS^T [0,16) | AO^T [16,32) tiles
//     ratio ratR = t1/t2; final finR[m] = t2/(2*1024)
// colRel epilogue also emits xrel8 = fp8(updated x_rel) (single writer).
// ---------------------------------------------------------------------------
__global__ __launch_bounds__(512, 4)
void gemmf8_dual(const unsigned char* __restrict__ Ao, const unsigned char* __restrict__ Bo,
                 float* __restrict__ Co,
                 const unsigned char* __restrict__ Ar, const unsigned char* __restrict__ Br,
                 float* __restrict__ Cr, unsigned char* __restrict__ xrel8out,
                 const float* __restrict__ rat1, const float* __restrict__ rat2,
                 const float* __restrict__ finO,
                 const float* __restrict__ ratR, const float* __restrict__ finR)
{
    __shared__ __align__(16) char lds[49152];

    const int tid  = threadIdx.x;
    const int lane = tid & 63;
    const int wid  = tid >> 6;
    const int wr = wid >> 2, wc = wid & 3;
    const int l15 = lane & 15, lk = lane >> 4;

    const int bid = blockIdx.x;                 // 1024, %8==0
    const int s   = (bid & 7) * 128 + (bid >> 3);

    const unsigned char* A; const unsigned char* B; float* C;
    const float* finP;
    int K, NT; long kb0; bool isObj;
    long rowM0, rowN0;
    if (s < 512) {          // colObj
        const int zz = s >> 6, t = s & 63;
        rowM0 = (long)(t >> 2) * 128; rowN0 = (long)(t & 3) * 256;
        A = Ao; B = Bo; C = Co; finP = finO;
        K = KOBJ; NT = 34; kb0 = (long)34 * zz * 128;
        isObj = true;
    } else {                // colRel
        const int t = s - 512;
        rowM0 = (long)(t >> 2) * 128; rowN0 = (long)(t & 3) * 256;
        A = Ar; B = Br; C = Cr; finP = finR;
        K = KREL; NT = 32; kb0 = 0;
        isObj = false;
    }
    const long ld = (long)K;
    const int g0 = (int)(kb0 >> 7);
    const int g1 = g0 + NT;

    const int rs = tid >> 3;
    const int kc = (tid & 7) ^ (rs & 7);
    const char* gA = (const char*)A + (rowM0 + rs) * ld + kb0 + kc * 16;
    const char* gB = (const char*)B + (rowN0 + rs) * ld + kb0 + kc * 16;
    char* lA = (char*)lds + tid * 16;
    char* lB = (char*)lds + 16384 + tid * 16;

    const int xc0 = ((2 * lk + 0) ^ (l15 & 7)) * 16;
    const int xc1 = ((2 * lk + 1) ^ (l15 & 7)) * 16;
    const int baseA = (wr * 64 + l15) * 128;
    const int baseB = 16384 + (wc * 64 + l15) * 128;

#define LDF8(dst, off) { \
    i32x4 lo_ = *(const i32x4*)((const char*)lds + (off) + xc0); \
    i32x4 hi_ = *(const i32x4*)((const char*)lds + (off) + xc1); \
    dst = __builtin_shufflevector(lo_, hi_, 0, 1, 2, 3, 4, 5, 6, 7); }

#define APPLY_RATIO(RP) { \
    _Pragma("unroll") \
    for (int kf = 0; kf < 4; kf++) { \
        const f32x4 rv = *(const f32x4*)((RP) + rowM0 + wr * 64 + kf * 16 + lk * 4); \
        _Pragma("unroll") \
        for (int j = 0; j < 4; j++) \
            _Pragma("unroll") \
            for (int r = 0; r < 4; r++) acc[kf][j][r] *= rv[r]; \
    } }

    f32x4 acc[4][4];
    #pragma unroll
    for (int i = 0; i < 4; i++)
        #pragma unroll
        for (int j = 0; j < 4; j++) acc[i][j] = f32x4{0.f, 0.f, 0.f, 0.f};

    for (int t = 0; t < NT; ++t) {
        const long kByte = (long)t * 128;
        gload_lds16(gA + kByte, lA);
        gload_lds16(gA + kByte + 64 * ld, lA + 8192);
        #pragma unroll
        for (int i = 0; i < 4; i++)
            gload_lds16(gB + kByte + (long)i * 64 * ld, lB + i * 8192);
        __syncthreads();

        i32x8 a[4];
        #pragma unroll
        for (int kf = 0; kf < 4; kf++) LDF8(a[kf], baseA + kf * 2048);
        #pragma unroll
        for (int j = 0; j < 4; j++) {
            i32x8 b;
            LDF8(b, baseB + j * 2048);
            #pragma unroll
            for (int kf = 0; kf < 4; kf++) MFMA_F8(acc[kf][j], a[kf], b);
        }

        // segment-boundary ratio rescale (wave-uniform branches)
        if (isObj) {
            const int g = g0 + t;
            if (g + 1 == 128 && g1 > 128) APPLY_RATIO(rat1);
            if (g + 1 == 256 && g1 > 256) APPLY_RATIO(rat2);
        } else {
            if (t + 1 == 16) APPLY_RATIO(ratR);
        }
        __syncthreads();
    }
    // boundaries past this block's K-range (block ends before boundary)
    if (isObj) {
        if (g0 < 128 && g1 <= 128) APPLY_RATIO(rat1);
        if (g0 < 256 && g1 <= 256) APPLY_RATIO(rat2);
    }
#undef LDF8
#undef APPLY_RATIO

    #pragma unroll
    for (int kf = 0; kf < 4; kf++) {
        const long m0 = rowM0 + wr * 64 + kf * 16 + lk * 4;
        const f32x4 fv = *(const f32x4*)(finP + m0);
        #pragma unroll
        for (int r = 0; r < 4; r++) {
            const long m = m0 + r;
            #pragma unroll
            for (int j = 0; j < 4; j++) {
                const long n = rowN0 + wc * 64 + j * 16 + l15;
                const float v = acc[kf][j][r] * fv[r];
                const long idx = m * (long)DIM + n;
                if (isObj) {
                    atomicAdd(&C[idx], v);
                } else {
                    const float nv = C[idx] + v;
                    C[idx] = nv;
                    xrel8out[idx] = fp8_byte(nv);
                }
            }
        }
    }
}

__global__ __launch_bounds__(256)
void k_cast_fp8(const float* __restrict__ in, unsigned char* __restrict__ out,
                long n, float scale)
{
    const long stride = (long)gridDim.x * blockDim.x;
    for (long i = (long)blockIdx.x * blockDim.x + threadIdx.x; i * 4 < n; i += stride) {
        f32x4 v = *reinterpret_cast<const f32x4*>(in + i * 4);
        *reinterpret_cast<unsigned*>(out + i * 4) =
            pk4_fp8(v[0] * scale, v[1] * scale, v[2] * scale, v[3] * scale);
    }
}

// ---------------------------------------------------------------------------
// Fused prologue pass: ONE read of f32 attn -> fp8(16*attn) straight copy,
// fp8(16*attn^T) transpose (if TRANS), exact f32 row-sum (+col-sum) atomics.
// ---------------------------------------------------------------------------
template<bool TRANS>
__global__ __launch_bounds__(256)
void k_prep16(const float* __restrict__ in, int C,
              unsigned char* __restrict__ Aobj, unsigned char* __restrict__ Arel,
              float* __restrict__ rowsum, float* __restrict__ colsum)
{
    __shared__ float tile[64][65];
    __shared__ float cpart[16][64];
    __shared__ float rpart[64][17];
    const int tid = threadIdx.x;
    const int tx  = tid & 15;
    const int ty  = tid >> 4;
    const long c0 = (long)blockIdx.x * 64;
    const long r0 = (long)blockIdx.y * 64;

    float cs0 = 0.f, cs1 = 0.f, cs2 = 0.f, cs3 = 0.f;
    #pragma unroll
    for (int i = 0; i < 4; i++) {
        const int r = i * 16 + ty;
        const f32x4 v = *reinterpret_cast<const f32x4*>(&in[(r0 + r) * (long)C + c0 + tx * 4]);
        *reinterpret_cast<unsigned*>(&Aobj[(r0 + r) * (long)KOBJ + c0 + tx * 4]) =
            pk4_fp8(v[0] * 16.f, v[1] * 16.f, v[2] * 16.f, v[3] * 16.f);
        rpart[r][tx] = v[0] + v[1] + v[2] + v[3];
        cs0 += v[0]; cs1 += v[1]; cs2 += v[2]; cs3 += v[3];
        if (TRANS) *reinterpret_cast<f32x4*>(&tile[r][tx * 4]) = v;
    }
    if (TRANS) {
        cpart[ty][tx * 4 + 0] = cs0;
        cpart[ty][tx * 4 + 1] = cs1;
        cpart[ty][tx * 4 + 2] = cs2;
        cpart[ty][tx * 4 + 3] = cs3;
    }
    __syncthreads();
    if (tid < 64) {
        float rsum = 0.f;
        #pragma unroll
        for (int k = 0; k < 16; k++) rsum += rpart[tid][k];
        atomicAdd(&rowsum[r0 + tid], rsum);
        if (TRANS) {
            float csum = 0.f;
            #pragma unroll
            for (int k = 0; k < 16; k++) csum += cpart[k][tid];
            atomicAdd(&colsum[c0 + tid], csum);
        }
    }
    if (TRANS) {
        const int rr = tid & 63;
        const int cg = tid >> 6;
        #pragma unroll
        for (int i = 0; i < 16; i++) {
            const int c = cg * 16 + i;
            Arel[(c0 + c) * (long)KREL + r0 + rr] = fp8_byte(tile[rr][c] * 16.f);
        }
    }
}

// scales from raw sums: rat1=s1/s2, rat2=s2/s3, finO=s3/3072; ratR=t1/t2, finR=t2/2048
__global__ __launch_bounds__(256)
void k_mkscales(const float* __restrict__ r1, const float* __restrict__ r2,
                const float* __restrict__ r3,
                float* __restrict__ rat1, float* __restrict__ rat2,
                float* __restrict__ fin, int n, float finDiv)
{
    const int i = blockIdx.x * 256 + threadIdx.x;
    if (i >= n) return;
    const float a = r1[i] + EPS, b = r2[i] + EPS;
    const float c = r3 ? (r3[i] + EPS) : b;
    rat1[i] = b / a;
    if (rat2) rat2[i] = c / b;
    fin[i] = 1.f / (c * finDiv);
}

extern "C" void kernel_launch(void* const* d_in, const int* in_sizes, int n_in,
                              void* d_out, int out_size, void* d_ws, size_t ws_size,
                              hipStream_t stream)
{
    if (n_in < 15) return;
    const float* obj_feats = (const float*)d_in[0];
    const float* rel_feats = (const float*)d_in[1];
    const float* attn_sub  = (const float*)d_in[2];
    const float* attn_obj  = (const float*)d_in[3];
    const float* attn_self = (const float*)d_in[4];
    const float* Wf[5] = { (const float*)d_in[5], (const float*)d_in[7],
                           (const float*)d_in[9], (const float*)d_in[11], (const float*)d_in[13] };
    const float* Bf[5] = { (const float*)d_in[6], (const float*)d_in[8],
                           (const float*)d_in[10], (const float*)d_in[12], (const float*)d_in[14] };

    const int NO = NOBJ, NR = NREL, D = DIM;

    char* w = (char*)d_ws;
    auto take = [&](size_t bytes) { char* p = w; w += bytes; return p; };
    unsigned char* Aobj8  = (unsigned char*)take((size_t)NO * KOBJ);
    unsigned char* Arel8  = (unsigned char*)take((size_t)NR * KREL);
    unsigned char* fcObj8 = (unsigned char*)take((size_t)D * KOBJ);
    unsigned char* fcRel8 = (unsigned char*)take((size_t)D * KREL);
    unsigned char* xrel8  = (unsigned char*)take((size_t)NR * D);
    unsigned char* xobj8  = (unsigned char*)take((size_t)NO * D);
    unsigned char* W018   = (unsigned char*)take((size_t)2 * D * D);
    unsigned char* W2348  = (unsigned char*)take((size_t)3 * D * D);
    float*  b01     = (float*)take((size_t)2 * D * 4);
    float*  bstk    = (float*)take((size_t)3 * D * 4);
    float*  sums    = (float*)take((size_t)(3 * NO + 2 * NR) * 4);   // raw sums
    float*  scl     = (float*)take((size_t)(3 * NO + 2 * NR) * 4);   // derived scales
    float* rsumS  = sums;                 // rowsum(attn_sub)
    float* rsumO  = sums + NO;            // rowsum(attn_obj)
    float* rsumSf = sums + 2 * NO;        // rowsum(attn_self)
    float* csumS  = sums + 3 * NO;        // colsum(attn_sub)
    float* csumO  = sums + 3 * NO + NR;   // colsum(attn_obj)
    float* rat1 = scl;                    // s1/s2 per obj row
    float* rat2 = scl + NO;               // s2/s3
    float* finO = scl + 2 * NO;           // s3/(3*1024)
    float* ratR = scl + 3 * NO;           // t1/t2 per rel row
    float* finR = scl + 3 * NO + NR;      // t2/(2*1024)
    if ((size_t)(w - (char*)d_ws) > ws_size) return;   // ws too small: fail loudly

    float* x_obj = (float*)d_out;
    float* x_rel = x_obj + (size_t)NO * D;

    hipMemcpyAsync(x_obj, obj_feats, (size_t)NO * D * 4, hipMemcpyDeviceToDevice, stream);
    hipMemcpyAsync(x_rel, rel_feats, (size_t)NR * D * 4, hipMemcpyDeviceToDevice, stream);
    hipMemcpyAsync(b01,     Bf[0], (size_t)D * 4, hipMemcpyDeviceToDevice, stream);
    hipMemcpyAsync(b01 + D, Bf[1], (size_t)D * 4, hipMemcpyDeviceToDevice, stream);
    for (int i = 0; i < 3; i++)
        hipMemcpyAsync(bstk + i * D, Bf[2 + i], (size_t)D * 4, hipMemcpyDeviceToDevice, stream);
    hipMemsetAsync(sums, 0, (size_t)(3 * NO + 2 * NR) * 4, stream);

    auto cast8 = [&](const float* in, unsigned char* out, long n, float sc) {
        long blocks = (n / 4 + 255) / 256; if (blocks > 4096) blocks = 4096;
        k_cast_fp8<<<dim3((unsigned)blocks), dim3(256), 0, stream>>>(in, out, n, sc);
    };
    cast8(Wf[0], W018,                 (long)D * D, 64.f);
    cast8(Wf[1], W018 + (size_t)D * D, (long)D * D, 64.f);
    for (int i = 0; i < 3; i++)
        cast8(Wf[2 + i], W2348 + (size_t)i * D * D, (long)D * D, 64.f);

    // fused single-pass prologue: fp8(16*attn) + transpose + exact sums
    k_prep16<true><<<dim3(NR / 64, NO / 64), dim3(256), 0, stream>>>(
        attn_sub, NR, Aobj8, Arel8, rsumS, csumS);
    k_prep16<true><<<dim3(NR / 64, NO / 64), dim3(256), 0, stream>>>(
        attn_obj, NR, Aobj8 + 16384, Arel8 + 2048, rsumO, csumO);
    k_prep16<false><<<dim3(NO / 64, NO / 64), dim3(256), 0, stream>>>(
        attn_self, NO, Aobj8 + 32768, nullptr, rsumSf, nullptr);

    // derived per-row scales
    k_mkscales<<<dim3((NO + 255) / 256), dim3(256), 0, stream>>>(
        rsumS, rsumO, rsumSf, rat1, rat2, finO, NO, 3072.f);
    k_mkscales<<<dim3((NR + 255) / 256), dim3(256), 0, stream>>>(
        csumS, csumO, nullptr, ratR, nullptr, finR, NR, 2048.f);

    // initial fp8 snapshot of x_rel (later steps get it from dual's epilogue)
    cast8(x_rel, xrel8, (long)NR * D, 1.f);

    for (int step = 0; step < 2; ++step) {
        cast8(x_obj, xobj8, (long)NO * D, 1.f);

        // all 5 FC layers in ONE dispatch (fc01 + f234 roles)
        gemmf8mlp<<<dim3(1216), dim3(512), 0, stream>>>(
            W018, xrel8, W2348, xobj8, b01, bstk, fcObj8, fcRel8);

        // both collects in ONE dispatch; colRel also emits xrel8 for next step
        gemmf8_dual<<<dim3(1024), dim3(512), 0, stream>>>(
            Aobj8, fcObj8, x_obj, Arel8, fcRel8, x_rel, xrel8,
            rat1, rat2, finO, ratR, finR);
    }
}

// Round 16
// 951.688 us; speedup vs baseline: 1.5215x; 1.5215x over previous
//
#include <hip/hip_runtime.h>
#include <hip/hip_bf16.h>

typedef __attribute__((ext_vector_type(4))) float  f32x4;
typedef __attribute__((ext_vector_type(4))) int    i32x4;
typedef __attribute__((ext_vector_type(8))) int    i32x8;

// problem constants
#define NOBJ 2048
#define NREL 16384
#define DIM  1024
#define KOBJ 34816   /* 16384 + 16384 + 2048 */
#define KREL 4096    /* 2048 + 2048 */
#define EPS  1e-7f

#define AS1Q __attribute__((address_space(1)))
#define AS3Q __attribute__((address_space(3)))

__device__ __forceinline__ void gload_lds16(const void* g, void* l) {
    __builtin_amdgcn_global_load_lds((AS1Q void*)const_cast<void*>(g),
                                     (AS3Q void*)l, 16, 0, 0);
}

// all-ones (E8M0 = 127) block scales: plain fp8 matmul at MX rate
#define MFMA_F8(ACC, Af, Bf) \
    ACC = __builtin_amdgcn_mfma_scale_f32_16x16x128_f8f6f4( \
        Af, Bf, ACC, 0, 0, 0, 0x7F7F7F7F, 0, 0x7F7F7F7F)

__device__ __forceinline__ unsigned char fp8_byte(float x) {
    return (unsigned char)(__builtin_amdgcn_cvt_pk_fp8_f32(x, x, 0, false) & 0xFF);
}
__device__ __forceinline__ unsigned pk4_fp8(float a, float b, float c, float d) {
    int v = __builtin_amdgcn_cvt_pk_fp8_f32(a, b, 0, false);
    v = __builtin_amdgcn_cvt_pk_fp8_f32(c, d, v, true);
    return (unsigned)v;
}

// ---------------------------------------------------------------------------
// Merged MX-fp8 FC kernel (fc01 + f234 in one dispatch), occ structure.
// (unchanged from R14 — 64 VGPR, no spill)
// ---------------------------------------------------------------------------
__global__ __launch_bounds__(512, 4)
void gemmf8mlp(const unsigned char* __restrict__ W01, const unsigned char* __restrict__ xrel8,
               const unsigned char* __restrict__ W234, const unsigned char* __restrict__ xobj8,
               const float* __restrict__ b01, const float* __restrict__ bstk,
               unsigned char* __restrict__ fcObj8, unsigned char* __restrict__ fcRel8)
{
    __shared__ __align__(16) char lds[49152];

    const int tid  = threadIdx.x;
    const int lane = tid & 63;
    const int wid  = tid >> 6;
    const int wr = wid >> 2, wc = wid & 3;
    const int l15 = lane & 15, lk = lane >> 4;

    const int bid = blockIdx.x;                 // 1216, %8==0
    const int s   = (bid & 7) * 152 + (bid >> 3);

    const unsigned char* A; const unsigned char* B; const float* bias; bool isFC;
    long rowM0, rowN0;
    if (s < 1024) {
        rowM0 = (long)(s >> 6) * 128;
        rowN0 = (long)(s & 63) * 256;
        A = W01; B = xrel8; bias = b01; isFC = true;
    } else {
        const int t = s - 1024;
        rowM0 = (long)(t >> 3) * 128;
        rowN0 = (long)(t & 7) * 256;
        A = W234; B = xobj8; bias = bstk; isFC = false;
    }
    const long ld = DIM;
    const int  NT = DIM >> 7;           // 8

    const int rs = tid >> 3;
    const int kc = (tid & 7) ^ (rs & 7);
    const char* gA = (const char*)A + (rowM0 + rs) * ld + kc * 16;
    const char* gB = (const char*)B + (rowN0 + rs) * ld + kc * 16;
    char* lA = (char*)lds + tid * 16;
    char* lB = (char*)lds + 16384 + tid * 16;

    const int xc0 = ((2 * lk + 0) ^ (l15 & 7)) * 16;
    const int xc1 = ((2 * lk + 1) ^ (l15 & 7)) * 16;
    const int baseA = (wr * 64 + l15) * 128;
    const int baseB = 16384 + (wc * 64 + l15) * 128;

#define LDF8(dst, off) { \
    i32x4 lo_ = *(const i32x4*)((const char*)lds + (off) + xc0); \
    i32x4 hi_ = *(const i32x4*)((const char*)lds + (off) + xc1); \
    dst = __builtin_shufflevector(lo_, hi_, 0, 1, 2, 3, 4, 5, 6, 7); }

    f32x4 acc[4][4];
    #pragma unroll
    for (int i = 0; i < 4; i++)
        #pragma unroll
        for (int j = 0; j < 4; j++) acc[i][j] = f32x4{0.f, 0.f, 0.f, 0.f};

    for (int t = 0; t < NT; ++t) {
        const long kByte = (long)t * 128;
        gload_lds16(gA + kByte, lA);
        gload_lds16(gA + kByte + 64 * ld, lA + 8192);
        #pragma unroll
        for (int i = 0; i < 4; i++)
            gload_lds16(gB + kByte + (long)i * 64 * ld, lB + i * 8192);
        __syncthreads();

        i32x8 a[4];
        #pragma unroll
        for (int kf = 0; kf < 4; kf++) LDF8(a[kf], baseA + kf * 2048);
        #pragma unroll
        for (int j = 0; j < 4; j++) {
            i32x8 b;
            LDF8(b, baseB + j * 2048);
            #pragma unroll
            for (int kf = 0; kf < 4; kf++) MFMA_F8(acc[kf][j], a[kf], b);
        }
        __syncthreads();
    }
#undef LDF8

    #pragma unroll
    for (int kf = 0; kf < 4; kf++) {
        const long m0 = rowM0 + wr * 64 + kf * 16 + lk * 4;
        #pragma unroll
        for (int r = 0; r < 4; r++) {
            const long m = m0 + r;
            const float bs = 64.f * bias[m];
            #pragma unroll
            for (int j = 0; j < 4; j++) {
                const long n = rowN0 + wc * 64 + j * 16 + l15;
                const float v = fmaxf(acc[kf][j][r] + bs, 0.f);
                const unsigned char o = fp8_byte(v);
                if (isFC) {
                    fcObj8[(m & 1023) * (long)KOBJ + (m >> 10) * 16384 + n] = o;
                } else {
                    if (m < 1024)       fcRel8[m * (long)KREL + n] = o;
                    else if (m < 2048)  fcRel8[(m - 1024) * (long)KREL + 2048 + n] = o;
                    else                fcObj8[(m - 2048) * (long)KOBJ + 32768 + n] = o;
                }
            }
        }
    }
}

// ---------------------------------------------------------------------------
// Dual-role 128x256 MX-fp8 collect kernel with segment-boundary acc rescale.
// launch_bounds (512,2): 128-VGPR cap — the R15 (512,4)=64-VGPR cap caused
// acc scratch-spill (WRITE_SIZE 147MB -> 987MB). Math verified in R15.
// ---------------------------------------------------------------------------
__global__ __launch_bounds__(512, 2)
void gemmf8_dual(const unsigned char* __restrict__ Ao, const unsigned char* __restrict__ Bo,
                 float* __restrict__ Co,
                 const unsigned char* __restrict__ Ar, const unsigned char* __restrict__ Br,
                 float* __restrict__ Cr, unsigned char* __restrict__ xrel8out,
                 const float* __restrict__ rat1, const float* __restrict__ rat2,
                 const float* __restrict__ finO,
                 const float* __restrict__ ratR, const float* __restrict__ finR)
{
    __shared__ __align__(16) char lds[49152];

    const int tid  = threadIdx.x;
    const int lane = tid & 63;
    const int wid  = tid >> 6;
    const int wr = wid >> 2, wc = wid & 3;
    const int l15 = lane & 15, lk = lane >> 4;

    const int bid = blockIdx.x;                 // 1024, %8==0
    const int s   = (bid & 7) * 128 + (bid >> 3);

    const unsigned char* A; const unsigned char* B; float* C;
    const float* finP;
    int K, NT; long kb0; bool isObj;
    long rowM0, rowN0;
    if (s < 512) {          // colObj
        const int zz = s >> 6, t = s & 63;
        rowM0 = (long)(t >> 2) * 128; rowN0 = (long)(t & 3) * 256;
        A = Ao; B = Bo; C = Co; finP = finO;
        K = KOBJ; NT = 34; kb0 = (long)34 * zz * 128;
        isObj = true;
    } else {                // colRel
        const int t = s - 512;
        rowM0 = (long)(t >> 2) * 128; rowN0 = (long)(t & 3) * 256;
        A = Ar; B = Br; C = Cr; finP = finR;
        K = KREL; NT = 32; kb0 = 0;
        isObj = false;
    }
    const long ld = (long)K;
    const int g0 = (int)(kb0 >> 7);
    const int g1 = g0 + NT;

    const int rs = tid >> 3;
    const int kc = (tid & 7) ^ (rs & 7);
    const char* gA = (const char*)A + (rowM0 + rs) * ld + kb0 + kc * 16;
    const char* gB = (const char*)B + (rowN0 + rs) * ld + kb0 + kc * 16;
    char* lA = (char*)lds + tid * 16;
    char* lB = (char*)lds + 16384 + tid * 16;

    const int xc0 = ((2 * lk + 0) ^ (l15 & 7)) * 16;
    const int xc1 = ((2 * lk + 1) ^ (l15 & 7)) * 16;
    const int baseA = (wr * 64 + l15) * 128;
    const int baseB = 16384 + (wc * 64 + l15) * 128;

#define LDF8(dst, off) { \
    i32x4 lo_ = *(const i32x4*)((const char*)lds + (off) + xc0); \
    i32x4 hi_ = *(const i32x4*)((const char*)lds + (off) + xc1); \
    dst = __builtin_shufflevector(lo_, hi_, 0, 1, 2, 3, 4, 5, 6, 7); }

#define APPLY_RATIO(RP) { \
    _Pragma("unroll") \
    for (int kf = 0; kf < 4; kf++) { \
        const f32x4 rv = *(const f32x4*)((RP) + rowM0 + wr * 64 + kf * 16 + lk * 4); \
        _Pragma("unroll") \
        for (int j = 0; j < 4; j++) \
            _Pragma("unroll") \
            for (int r = 0; r < 4; r++) acc[kf][j][r] *= rv[r]; \
    } }

    f32x4 acc[4][4];
    #pragma unroll
    for (int i = 0; i < 4; i++)
        #pragma unroll
        for (int j = 0; j < 4; j++) acc[i][j] = f32x4{0.f, 0.f, 0.f, 0.f};

    for (int t = 0; t < NT; ++t) {
        const long kByte = (long)t * 128;
        gload_lds16(gA + kByte, lA);
        gload_lds16(gA + kByte + 64 * ld, lA + 8192);
        #pragma unroll
        for (int i = 0; i < 4; i++)
            gload_lds16(gB + kByte + (long)i * 64 * ld, lB + i * 8192);
        __syncthreads();

        i32x8 a[4];
        #pragma unroll
        for (int kf = 0; kf < 4; kf++) LDF8(a[kf], baseA + kf * 2048);
        #pragma unroll
        for (int j = 0; j < 4; j++) {
            i32x8 b;
            LDF8(b, baseB + j * 2048);
            #pragma unroll
            for (int kf = 0; kf < 4; kf++) MFMA_F8(acc[kf][j], a[kf], b);
        }

        // segment-boundary ratio rescale (wave-uniform branches)
        if (isObj) {
            const int g = g0 + t;
            if (g + 1 == 128 && g1 > 128) APPLY_RATIO(rat1);
            if (g + 1 == 256 && g1 > 256) APPLY_RATIO(rat2);
        } else {
            if (t + 1 == 16) APPLY_RATIO(ratR);
        }
        __syncthreads();
    }
    // boundaries past this block's K-range (block ends before boundary)
    if (isObj) {
        if (g0 < 128 && g1 <= 128) APPLY_RATIO(rat1);
        if (g0 < 256 && g1 <= 256) APPLY_RATIO(rat2);
    }
#undef LDF8
#undef APPLY_RATIO

    #pragma unroll
    for (int kf = 0; kf < 4; kf++) {
        const long m0 = rowM0 + wr * 64 + kf * 16 + lk * 4;
        const f32x4 fv = *(const f32x4*)(finP + m0);
        #pragma unroll
        for (int r = 0; r < 4; r++) {
            const long m = m0 + r;
            #pragma unroll
            for (int j = 0; j < 4; j++) {
                const long n = rowN0 + wc * 64 + j * 16 + l15;
                const float v = acc[kf][j][r] * fv[r];
                const long idx = m * (long)DIM + n;
                if (isObj) {
                    atomicAdd(&C[idx], v);
                } else {
                    const float nv = C[idx] + v;
                    C[idx] = nv;
                    xrel8out[idx] = fp8_byte(nv);
                }
            }
        }
    }
}

__global__ __launch_bounds__(256)
void k_cast_fp8(const float* __restrict__ in, unsigned char* __restrict__ out,
                long n, float scale)
{
    const long stride = (long)gridDim.x * blockDim.x;
    for (long i = (long)blockIdx.x * blockDim.x + threadIdx.x; i * 4 < n; i += stride) {
        f32x4 v = *reinterpret_cast<const f32x4*>(in + i * 4);
        *reinterpret_cast<unsigned*>(out + i * 4) =
            pk4_fp8(v[0] * scale, v[1] * scale, v[2] * scale, v[3] * scale);
    }
}

// ---------------------------------------------------------------------------
// Fused prologue pass: ONE read of f32 attn -> fp8(16*attn) straight copy,
// fp8(16*attn^T) transpose (if TRANS), exact f32 row-sum (+col-sum) atomics.
// ---------------------------------------------------------------------------
template<bool TRANS>
__global__ __launch_bounds__(256)
void k_prep16(const float* __restrict__ in, int C,
              unsigned char* __restrict__ Aobj, unsigned char* __restrict__ Arel,
              float* __restrict__ rowsum, float* __restrict__ colsum)
{
    __shared__ float tile[64][65];
    __shared__ float cpart[16][64];
    __shared__ float rpart[64][17];
    const int tid = threadIdx.x;
    const int tx  = tid & 15;
    const int ty  = tid >> 4;
    const long c0 = (long)blockIdx.x * 64;
    const long r0 = (long)blockIdx.y * 64;

    float cs0 = 0.f, cs1 = 0.f, cs2 = 0.f, cs3 = 0.f;
    #pragma unroll
    for (int i = 0; i < 4; i++) {
        const int r = i * 16 + ty;
        const f32x4 v = *reinterpret_cast<const f32x4*>(&in[(r0 + r) * (long)C + c0 + tx * 4]);
        *reinterpret_cast<unsigned*>(&Aobj[(r0 + r) * (long)KOBJ + c0 + tx * 4]) =
            pk4_fp8(v[0] * 16.f, v[1] * 16.f, v[2] * 16.f, v[3] * 16.f);
        rpart[r][tx] = v[0] + v[1] + v[2] + v[3];
        cs0 += v[0]; cs1 += v[1]; cs2 += v[2]; cs3 += v[3];
        if (TRANS) *reinterpret_cast<f32x4*>(&tile[r][tx * 4]) = v;
    }
    if (TRANS) {
        cpart[ty][tx * 4 + 0] = cs0;
        cpart[ty][tx * 4 + 1] = cs1;
        cpart[ty][tx * 4 + 2] = cs2;
        cpart[ty][tx * 4 + 3] = cs3;
    }
    __syncthreads();
    if (tid < 64) {
        float rsum = 0.f;
        #pragma unroll
        for (int k = 0; k < 16; k++) rsum += rpart[tid][k];
        atomicAdd(&rowsum[r0 + tid], rsum);
        if (TRANS) {
            float csum = 0.f;
            #pragma unroll
            for (int k = 0; k < 16; k++) csum += cpart[k][tid];
            atomicAdd(&colsum[c0 + tid], csum);
        }
    }
    if (TRANS) {
        const int rr = tid & 63;
        const int cg = tid >> 6;
        #pragma unroll
        for (int i = 0; i < 16; i++) {
            const int c = cg * 16 + i;
            Arel[(c0 + c) * (long)KREL + r0 + rr] = fp8_byte(tile[rr][c] * 16.f);
        }
    }
}

// scales from raw sums: rat1=s1/s2, rat2=s2/s3, finO=s3/3072; ratR=t1/t2, finR=t2/2048
__global__ __launch_bounds__(256)
void k_mkscales(const float* __restrict__ r1, const float* __restrict__ r2,
                const float* __restrict__ r3,
                float* __restrict__ rat1, float* __restrict__ rat2,
                float* __restrict__ fin, int n, float finDiv)
{
    const int i = blockIdx.x * 256 + threadIdx.x;
    if (i >= n) return;
    const float a = r1[i] + EPS, b = r2[i] + EPS;
    const float c = r3 ? (r3[i] + EPS) : b;
    rat1[i] = b / a;
    if (rat2) rat2[i] = c / b;
    fin[i] = 1.f / (c * finDiv);
}

extern "C" void kernel_launch(void* const* d_in, const int* in_sizes, int n_in,
                              void* d_out, int out_size, void* d_ws, size_t ws_size,
                              hipStream_t stream)
{
    if (n_in < 15) return;
    const float* obj_feats = (const float*)d_in[0];
    const float* rel_feats = (const float*)d_in[1];
    const float* attn_sub  = (const float*)d_in[2];
    const float* attn_obj  = (const float*)d_in[3];
    const float* attn_self = (const float*)d_in[4];
    const float* Wf[5] = { (const float*)d_in[5], (const float*)d_in[7],
                           (const float*)d_in[9], (const float*)d_in[11], (const float*)d_in[13] };
    const float* Bf[5] = { (const float*)d_in[6], (const float*)d_in[8],
                           (const float*)d_in[10], (const float*)d_in[12], (const float*)d_in[14] };

    const int NO = NOBJ, NR = NREL, D = DIM;

    char* w = (char*)d_ws;
    auto take = [&](size_t bytes) { char* p = w; w += bytes; return p; };
    unsigned char* Aobj8  = (unsigned char*)take((size_t)NO * KOBJ);
    unsigned char* Arel8  = (unsigned char*)take((size_t)NR * KREL);
    unsigned char* fcObj8 = (unsigned char*)take((size_t)D * KOBJ);
    unsigned char* fcRel8 = (unsigned char*)take((size_t)D * KREL);
    unsigned char* xrel8  = (unsigned char*)take((size_t)NR * D);
    unsigned char* xobj8  = (unsigned char*)take((size_t)NO * D);
    unsigned char* W018   = (unsigned char*)take((size_t)2 * D * D);
    unsigned char* W2348  = (unsigned char*)take((size_t)3 * D * D);
    float*  b01     = (float*)take((size_t)2 * D * 4);
    float*  bstk    = (float*)take((size_t)3 * D * 4);
    float*  sums    = (float*)take((size_t)(3 * NO + 2 * NR) * 4);   // raw sums
    float*  scl     = (float*)take((size_t)(3 * NO + 2 * NR) * 4);   // derived scales
    float* rsumS  = sums;
    float* rsumO  = sums + NO;
    float* rsumSf = sums + 2 * NO;
    float* csumS  = sums + 3 * NO;
    float* csumO  = sums + 3 * NO + NR;
    float* rat1 = scl;
    float* rat2 = scl + NO;
    float* finO = scl + 2 * NO;
    float* ratR = scl + 3 * NO;
    float* finR = scl + 3 * NO + NR;
    if ((size_t)(w - (char*)d_ws) > ws_size) return;   // ws too small: fail loudly

    float* x_obj = (float*)d_out;
    float* x_rel = x_obj + (size_t)NO * D;

    hipMemcpyAsync(x_obj, obj_feats, (size_t)NO * D * 4, hipMemcpyDeviceToDevice, stream);
    hipMemcpyAsync(x_rel, rel_feats, (size_t)NR * D * 4, hipMemcpyDeviceToDevice, stream);
    hipMemcpyAsync(b01,     Bf[0], (size_t)D * 4, hipMemcpyDeviceToDevice, stream);
    hipMemcpyAsync(b01 + D, Bf[1], (size_t)D * 4, hipMemcpyDeviceToDevice, stream);
    for (int i = 0; i < 3; i++)
        hipMemcpyAsync(bstk + i * D, Bf[2 + i], (size_t)D * 4, hipMemcpyDeviceToDevice, stream);
    hipMemsetAsync(sums, 0, (size_t)(3 * NO + 2 * NR) * 4, stream);

    auto cast8 = [&](const float* in, unsigned char* out, long n, float sc) {
        long blocks = (n / 4 + 255) / 256; if (blocks > 4096) blocks = 4096;
        k_cast_fp8<<<dim3((unsigned)blocks), dim3(256), 0, stream>>>(in, out, n, sc);
    };
    cast8(Wf[0], W018,                 (long)D * D, 64.f);
    cast8(Wf[1], W018 + (size_t)D * D, (long)D * D, 64.f);
    for (int i = 0; i < 3; i++)
        cast8(Wf[2 + i], W2348 + (size_t)i * D * D, (long)D * D, 64.f);

    // fused single-pass prologue: fp8(16*attn) + transpose + exact sums
    k_prep16<true><<<dim3(NR / 64, NO / 64), dim3(256), 0, stream>>>(
        attn_sub, NR, Aobj8, Arel8, rsumS, csumS);
    k_prep16<true><<<dim3(NR / 64, NO / 64), dim3(256), 0, stream>>>(
        attn_obj, NR, Aobj8 + 16384, Arel8 + 2048, rsumO, csumO);
    k_prep16<false><<<dim3(NO / 64, NO / 64), dim3(256), 0, stream>>>(
        attn_self, NO, Aobj8 + 32768, nullptr, rsumSf, nullptr);

    // derived per-row scales
    k_mkscales<<<dim3((NO + 255) / 256), dim3(256), 0, stream>>>(
        rsumS, rsumO, rsumSf, rat1, rat2, finO, NO, 3072.f);
    k_mkscales<<<dim3((NR + 255) / 256), dim3(256), 0, stream>>>(
        csumS, csumO, nullptr, ratR, nullptr, finR, NR, 2048.f);

    // initial fp8 snapshot of x_rel (later steps get it from dual's epilogue)
    cast8(x_rel, xrel8, (long)NR * D, 1.f);

    for (int step = 0; step < 2; ++step) {
        cast8(x_obj, xobj8, (long)NO * D, 1.f);

        // all 5 FC layers in ONE dispatch (fc01 + f234 roles)
        gemmf8mlp<<<dim3(1216), dim3(512), 0, stream>>>(
            W018, xrel8, W2348, xobj8, b01, bstk, fcObj8, fcRel8);

        // both collects in ONE dispatch; colRel also emits xrel8 for next step
        gemmf8_dual<<<dim3(1024), dim3(512), 0, stream>>>(
            Aobj8, fcObj8, x_obj, Arel8, fcRel8, x_rel, xrel8,
            rat1, rat2, finO, ratR, finR);
    }
}

// Round 17
// 826.289 us; speedup vs baseline: 1.7524x; 1.1518x over previous
//
#include <hip/hip_runtime.h>
#include <hip/hip_bf16.h>

typedef __attribute__((ext_vector_type(4))) float  f32x4;
typedef __attribute__((ext_vector_type(4))) int    i32x4;
typedef __attribute__((ext_vector_type(8))) int    i32x8;

// problem constants
#define NOBJ 2048
#define NREL 16384
#define DIM  1024
#define KOBJ 34816   /* 16384 + 16384 + 2048 */
#define KREL 4096    /* 2048 + 2048 */
#define EPS  1e-7f

#define AS1Q __attribute__((address_space(1)))
#define AS3Q __attribute__((address_space(3)))

__device__ __forceinline__ void gload_lds16(const void* g, void* l) {
    __builtin_amdgcn_global_load_lds((AS1Q void*)const_cast<void*>(g),
                                     (AS3Q void*)l, 16, 0, 0);
}

// all-ones (E8M0 = 127) block scales: plain fp8 matmul at MX rate
#define MFMA_F8(ACC, Af, Bf) \
    ACC = __builtin_amdgcn_mfma_scale_f32_16x16x128_f8f6f4( \
        Af, Bf, ACC, 0, 0, 0, 0x7F7F7F7F, 0, 0x7F7F7F7F)

__device__ __forceinline__ unsigned char fp8_byte(float x) {
    return (unsigned char)(__builtin_amdgcn_cvt_pk_fp8_f32(x, x, 0, false) & 0xFF);
}
__device__ __forceinline__ unsigned pk4_fp8(float a, float b, float c, float d) {
    int v = __builtin_amdgcn_cvt_pk_fp8_f32(a, b, 0, false);
    v = __builtin_amdgcn_cvt_pk_fp8_f32(c, d, v, true);
    return (unsigned)v;
}

// ---------------------------------------------------------------------------
// Merged MX-fp8 FC kernel (fc01 + f234 in one dispatch), occ structure.
// (unchanged — 64 VGPR, no spill)
// ---------------------------------------------------------------------------
__global__ __launch_bounds__(512, 4)
void gemmf8mlp(const unsigned char* __restrict__ W01, const unsigned char* __restrict__ xrel8,
               const unsigned char* __restrict__ W234, const unsigned char* __restrict__ xobj8,
               const float* __restrict__ b01, const float* __restrict__ bstk,
               unsigned char* __restrict__ fcObj8, unsigned char* __restrict__ fcRel8)
{
    __shared__ __align__(16) char lds[49152];

    const int tid  = threadIdx.x;
    const int lane = tid & 63;
    const int wid  = tid >> 6;
    const int wr = wid >> 2, wc = wid & 3;
    const int l15 = lane & 15, lk = lane >> 4;

    const int bid = blockIdx.x;                 // 1216, %8==0
    const int s   = (bid & 7) * 152 + (bid >> 3);

    const unsigned char* A; const unsigned char* B; const float* bias; bool isFC;
    long rowM0, rowN0;
    if (s < 1024) {
        rowM0 = (long)(s >> 6) * 128;
        rowN0 = (long)(s & 63) * 256;
        A = W01; B = xrel8; bias = b01; isFC = true;
    } else {
        const int t = s - 1024;
        rowM0 = (long)(t >> 3) * 128;
        rowN0 = (long)(t & 7) * 256;
        A = W234; B = xobj8; bias = bstk; isFC = false;
    }
    const long ld = DIM;
    const int  NT = DIM >> 7;           // 8

    const int rs = tid >> 3;
    const int kc = (tid & 7) ^ (rs & 7);
    const char* gA = (const char*)A + (rowM0 + rs) * ld + kc * 16;
    const char* gB = (const char*)B + (rowN0 + rs) * ld + kc * 16;
    char* lA = (char*)lds + tid * 16;
    char* lB = (char*)lds + 16384 + tid * 16;

    const int xc0 = ((2 * lk + 0) ^ (l15 & 7)) * 16;
    const int xc1 = ((2 * lk + 1) ^ (l15 & 7)) * 16;
    const int baseA = (wr * 64 + l15) * 128;
    const int baseB = 16384 + (wc * 64 + l15) * 128;

#define LDF8(dst, off) { \
    i32x4 lo_ = *(const i32x4*)((const char*)lds + (off) + xc0); \
    i32x4 hi_ = *(const i32x4*)((const char*)lds + (off) + xc1); \
    dst = __builtin_shufflevector(lo_, hi_, 0, 1, 2, 3, 4, 5, 6, 7); }

    f32x4 acc[4][4];
    #pragma unroll
    for (int i = 0; i < 4; i++)
        #pragma unroll
        for (int j = 0; j < 4; j++) acc[i][j] = f32x4{0.f, 0.f, 0.f, 0.f};

    for (int t = 0; t < NT; ++t) {
        const long kByte = (long)t * 128;
        gload_lds16(gA + kByte, lA);
        gload_lds16(gA + kByte + 64 * ld, lA + 8192);
        #pragma unroll
        for (int i = 0; i < 4; i++)
            gload_lds16(gB + kByte + (long)i * 64 * ld, lB + i * 8192);
        __syncthreads();

        i32x8 a[4];
        #pragma unroll
        for (int kf = 0; kf < 4; kf++) LDF8(a[kf], baseA + kf * 2048);
        #pragma unroll
        for (int j = 0; j < 4; j++) {
            i32x8 b;
            LDF8(b, baseB + j * 2048);
            #pragma unroll
            for (int kf = 0; kf < 4; kf++) MFMA_F8(acc[kf][j], a[kf], b);
        }
        __syncthreads();
    }
#undef LDF8

    #pragma unroll
    for (int kf = 0; kf < 4; kf++) {
        const long m0 = rowM0 + wr * 64 + kf * 16 + lk * 4;
        #pragma unroll
        for (int r = 0; r < 4; r++) {
            const long m = m0 + r;
            const float bs = 64.f * bias[m];
            #pragma unroll
            for (int j = 0; j < 4; j++) {
                const long n = rowN0 + wc * 64 + j * 16 + l15;
                const float v = fmaxf(acc[kf][j][r] + bs, 0.f);
                const unsigned char o = fp8_byte(v);
                if (isFC) {
                    fcObj8[(m & 1023) * (long)KOBJ + (m >> 10) * 16384 + n] = o;
                } else {
                    if (m < 1024)       fcRel8[m * (long)KREL + n] = o;
                    else if (m < 2048)  fcRel8[(m - 1024) * (long)KREL + 2048 + n] = o;
                    else                fcObj8[(m - 2048) * (long)KOBJ + 32768 + n] = o;
                }
            }
        }
    }
}

// ---------------------------------------------------------------------------
// Dual-role 128x256 MX-fp8 collect kernel, SEGMENT-ALIGNED split-K:
// each colObj block covers exactly ONE attn segment, so its per-row scale
// applies purely in the epilogue (no in-loop state -> 64-VGPR K-loop = R14).
// 1088 blocks:
//   s<256:     colObj/AS  z=s>>6 (4 z x 32 tiles), kb0=z*32 tiles,  fin=finS
//   s<512:     colObj/AO  z=(s-256)>>6,            kb0=128+z*32,    fin=finO2
//   s<576:     colObj/Self (64 tiles),             kb0=256, NT=16,  fin=finSf
//   else:      colRel (512 tiles), NT=32, single in-loop rescale at t==15
//              (ratR), single-writer += and xrel8 emit, fin=finR
// ---------------------------------------------------------------------------
__global__ __launch_bounds__(512, 4)
void gemmf8_dual(const unsigned char* __restrict__ Ao, const unsigned char* __restrict__ Bo,
                 float* __restrict__ Co,
                 const unsigned char* __restrict__ Ar, const unsigned char* __restrict__ Br,
                 float* __restrict__ Cr, unsigned char* __restrict__ xrel8out,
                 const float* __restrict__ finS, const float* __restrict__ finO2,
                 const float* __restrict__ finSf,
                 const float* __restrict__ ratR, const float* __restrict__ finR)
{
    __shared__ __align__(16) char lds[49152];

    const int tid  = threadIdx.x;
    const int lane = tid & 63;
    const int wid  = tid >> 6;
    const int wr = wid >> 2, wc = wid & 3;
    const int l15 = lane & 15, lk = lane >> 4;

    const int bid = blockIdx.x;                 // 1088, %8==0
    const int s   = (bid & 7) * 136 + (bid >> 3);

    const unsigned char* A; const unsigned char* B; float* C;
    const float* finP;
    int K, NT; long kb0; bool isObj;
    long rowM0, rowN0;
    if (s < 576) {          // colObj, one segment per block
        int t;
        if (s < 256)      { t = s & 63; kb0 = (long)((s >> 6) * 32) * 128;        NT = 32; finP = finS; }
        else if (s < 512) { const int q = s - 256; t = q & 63;
                            kb0 = (long)(128 + (q >> 6) * 32) * 128;              NT = 32; finP = finO2; }
        else              { t = s - 512; kb0 = (long)256 * 128;                   NT = 16; finP = finSf; }
        rowM0 = (long)(t >> 2) * 128; rowN0 = (long)(t & 3) * 256;
        A = Ao; B = Bo; C = Co; K = KOBJ; isObj = true;
    } else {                // colRel
        const int t = s - 576;
        rowM0 = (long)(t >> 2) * 128; rowN0 = (long)(t & 3) * 256;
        A = Ar; B = Br; C = Cr; finP = finR;
        K = KREL; NT = 32; kb0 = 0; isObj = false;
    }
    const long ld = (long)K;

    const int rs = tid >> 3;
    const int kc = (tid & 7) ^ (rs & 7);
    const char* gA = (const char*)A + (rowM0 + rs) * ld + kb0 + kc * 16;
    const char* gB = (const char*)B + (rowN0 + rs) * ld + kb0 + kc * 16;
    char* lA = (char*)lds + tid * 16;
    char* lB = (char*)lds + 16384 + tid * 16;

    const int xc0 = ((2 * lk + 0) ^ (l15 & 7)) * 16;
    const int xc1 = ((2 * lk + 1) ^ (l15 & 7)) * 16;
    const int baseA = (wr * 64 + l15) * 128;
    const int baseB = 16384 + (wc * 64 + l15) * 128;

#define LDF8(dst, off) { \
    i32x4 lo_ = *(const i32x4*)((const char*)lds + (off) + xc0); \
    i32x4 hi_ = *(const i32x4*)((const char*)lds + (off) + xc1); \
    dst = __builtin_shufflevector(lo_, hi_, 0, 1, 2, 3, 4, 5, 6, 7); }

    f32x4 acc[4][4];
    #pragma unroll
    for (int i = 0; i < 4; i++)
        #pragma unroll
        for (int j = 0; j < 4; j++) acc[i][j] = f32x4{0.f, 0.f, 0.f, 0.f};

    for (int t = 0; t < NT; ++t) {
        const long kByte = (long)t * 128;
        gload_lds16(gA + kByte, lA);
        gload_lds16(gA + kByte + 64 * ld, lA + 8192);
        #pragma unroll
        for (int i = 0; i < 4; i++)
            gload_lds16(gB + kByte + (long)i * 64 * ld, lB + i * 8192);
        __syncthreads();

        i32x8 a[4];
        #pragma unroll
        for (int kf = 0; kf < 4; kf++) LDF8(a[kf], baseA + kf * 2048);
        #pragma unroll
        for (int j = 0; j < 4; j++) {
            i32x8 b;
            LDF8(b, baseB + j * 2048);
            #pragma unroll
            for (int kf = 0; kf < 4; kf++) MFMA_F8(acc[kf][j], a[kf], b);
        }

        // colRel only: segment boundary at t==15 (wave-uniform, single ratio)
        if (!isObj && t == 15) {
            #pragma unroll
            for (int kf = 0; kf < 4; kf++) {
                const f32x4 rv = *(const f32x4*)(ratR + rowM0 + wr * 64 + kf * 16 + lk * 4);
                #pragma unroll
                for (int j = 0; j < 4; j++)
                    #pragma unroll
                    for (int r = 0; r < 4; r++) acc[kf][j][r] *= rv[r];
            }
        }
        __syncthreads();
    }
#undef LDF8

    #pragma unroll
    for (int kf = 0; kf < 4; kf++) {
        const long m0 = rowM0 + wr * 64 + kf * 16 + lk * 4;
        const f32x4 fv = *(const f32x4*)(finP + m0);
        #pragma unroll
        for (int r = 0; r < 4; r++) {
            const long m = m0 + r;
            #pragma unroll
            for (int j = 0; j < 4; j++) {
                const long n = rowN0 + wc * 64 + j * 16 + l15;
                const float v = acc[kf][j][r] * fv[r];
                const long idx = m * (long)DIM + n;
                if (isObj) {
                    atomicAdd(&C[idx], v);
                } else {
                    const float nv = C[idx] + v;
                    C[idx] = nv;
                    xrel8out[idx] = fp8_byte(nv);
                }
            }
        }
    }
}

__global__ __launch_bounds__(256)
void k_cast_fp8(const float* __restrict__ in, unsigned char* __restrict__ out,
                long n, float scale)
{
    const long stride = (long)gridDim.x * blockDim.x;
    for (long i = (long)blockIdx.x * blockDim.x + threadIdx.x; i * 4 < n; i += stride) {
        f32x4 v = *reinterpret_cast<const f32x4*>(in + i * 4);
        *reinterpret_cast<unsigned*>(out + i * 4) =
            pk4_fp8(v[0] * scale, v[1] * scale, v[2] * scale, v[3] * scale);
    }
}

// ---------------------------------------------------------------------------
// Fused prologue pass: ONE read of f32 attn -> fp8(16*attn) straight copy,
// fp8(16*attn^T) transpose (if TRANS), exact f32 row-sum (+col-sum) atomics.
// ---------------------------------------------------------------------------
template<bool TRANS>
__global__ __launch_bounds__(256)
void k_prep16(const float* __restrict__ in, int C,
              unsigned char* __restrict__ Aobj, unsigned char* __restrict__ Arel,
              float* __restrict__ rowsum, float* __restrict__ colsum)
{
    __shared__ float tile[64][65];
    __shared__ float cpart[16][64];
    __shared__ float rpart[64][17];
    const int tid = threadIdx.x;
    const int tx  = tid & 15;
    const int ty  = tid >> 4;
    const long c0 = (long)blockIdx.x * 64;
    const long r0 = (long)blockIdx.y * 64;

    float cs0 = 0.f, cs1 = 0.f, cs2 = 0.f, cs3 = 0.f;
    #pragma unroll
    for (int i = 0; i < 4; i++) {
        const int r = i * 16 + ty;
        const f32x4 v = *reinterpret_cast<const f32x4*>(&in[(r0 + r) * (long)C + c0 + tx * 4]);
        *reinterpret_cast<unsigned*>(&Aobj[(r0 + r) * (long)KOBJ + c0 + tx * 4]) =
            pk4_fp8(v[0] * 16.f, v[1] * 16.f, v[2] * 16.f, v[3] * 16.f);
        rpart[r][tx] = v[0] + v[1] + v[2] + v[3];
        cs0 += v[0]; cs1 += v[1]; cs2 += v[2]; cs3 += v[3];
        if (TRANS) *reinterpret_cast<f32x4*>(&tile[r][tx * 4]) = v;
    }
    if (TRANS) {
        cpart[ty][tx * 4 + 0] = cs0;
        cpart[ty][tx * 4 + 1] = cs1;
        cpart[ty][tx * 4 + 2] = cs2;
        cpart[ty][tx * 4 + 3] = cs3;
    }
    __syncthreads();
    if (tid < 64) {
        float rsum = 0.f;
        #pragma unroll
        for (int k = 0; k < 16; k++) rsum += rpart[tid][k];
        atomicAdd(&rowsum[r0 + tid], rsum);
        if (TRANS) {
            float csum = 0.f;
            #pragma unroll
            for (int k = 0; k < 16; k++) csum += cpart[k][tid];
            atomicAdd(&colsum[c0 + tid], csum);
        }
    }
    if (TRANS) {
        const int rr = tid & 63;
        const int cg = tid >> 6;
        #pragma unroll
        for (int i = 0; i < 16; i++) {
            const int c = cg * 16 + i;
            Arel[(c0 + c) * (long)KREL + r0 + rr] = fp8_byte(tile[rr][c] * 16.f);
        }
    }
}

// fin[i] = 1 / ((sum[i]+EPS) * div)   (applied to 3*NO contiguous obj sums)
__global__ __launch_bounds__(256)
void k_mkfin(const float* __restrict__ sum, float* __restrict__ fin, int n, float div)
{
    const int i = blockIdx.x * 256 + threadIdx.x;
    if (i < n) fin[i] = 1.f / ((sum[i] + EPS) * div);
}

// ratR = (csumO+EPS)/(csumS+EPS); finR = 1/(2048*(csumO+EPS))
__global__ __launch_bounds__(256)
void k_mkrel(const float* __restrict__ csumS, const float* __restrict__ csumO,
             float* __restrict__ ratR, float* __restrict__ finR, int n)
{
    const int i = blockIdx.x * 256 + threadIdx.x;
    if (i >= n) return;
    const float a = csumS[i] + EPS, b = csumO[i] + EPS;
    ratR[i] = b / a;
    finR[i] = 1.f / (2048.f * b);
}

extern "C" void kernel_launch(void* const* d_in, const int* in_sizes, int n_in,
                              void* d_out, int out_size, void* d_ws, size_t ws_size,
                              hipStream_t stream)
{
    if (n_in < 15) return;
    const float* obj_feats = (const float*)d_in[0];
    const float* rel_feats = (const float*)d_in[1];
    const float* attn_sub  = (const float*)d_in[2];
    const float* attn_obj  = (const float*)d_in[3];
    const float* attn_self = (const float*)d_in[4];
    const float* Wf[5] = { (const float*)d_in[5], (const float*)d_in[7],
                           (const float*)d_in[9], (const float*)d_in[11], (const float*)d_in[13] };
    const float* Bf[5] = { (const float*)d_in[6], (const float*)d_in[8],
                           (const float*)d_in[10], (const float*)d_in[12], (const float*)d_in[14] };

    const int NO = NOBJ, NR = NREL, D = DIM;

    char* w = (char*)d_ws;
    auto take = [&](size_t bytes) { char* p = w; w += bytes; return p; };
    unsigned char* Aobj8  = (unsigned char*)take((size_t)NO * KOBJ);
    unsigned char* Arel8  = (unsigned char*)take((size_t)NR * KREL);
    unsigned char* fcObj8 = (unsigned char*)take((size_t)D * KOBJ);
    unsigned char* fcRel8 = (unsigned char*)take((size_t)D * KREL);
    unsigned char* xrel8  = (unsigned char*)take((size_t)NR * D);
    unsigned char* xobj8  = (unsigned char*)take((size_t)NO * D);
    unsigned char* W018   = (unsigned char*)take((size_t)2 * D * D);
    unsigned char* W2348  = (unsigned char*)take((size_t)3 * D * D);
    float*  b01     = (float*)take((size_t)2 * D * 4);
    float*  bstk    = (float*)take((size_t)3 * D * 4);
    float*  sums    = (float*)take((size_t)(3 * NO + 2 * NR) * 4);   // raw sums
    float*  scl     = (float*)take((size_t)(3 * NO + 2 * NR) * 4);   // derived scales
    float* rsumS  = sums;
    float* csumS  = sums + 3 * NO;
    float* csumO  = sums + 3 * NO + NR;
    float* finS   = scl;                  // 1/(3072*(rsumS+eps))
    float* finO2  = scl + NO;             // 1/(3072*(rsumO+eps))
    float* finSf  = scl + 2 * NO;         // 1/(3072*(rsumSf+eps))
    float* ratR   = scl + 3 * NO;         // (csumO+eps)/(csumS+eps)
    float* finR   = scl + 3 * NO + NR;    // 1/(2048*(csumO+eps))
    if ((size_t)(w - (char*)d_ws) > ws_size) return;   // ws too small: fail loudly

    float* x_obj = (float*)d_out;
    float* x_rel = x_obj + (size_t)NO * D;

    hipMemcpyAsync(x_obj, obj_feats, (size_t)NO * D * 4, hipMemcpyDeviceToDevice, stream);
    hipMemcpyAsync(x_rel, rel_feats, (size_t)NR * D * 4, hipMemcpyDeviceToDevice, stream);
    hipMemcpyAsync(b01,     Bf[0], (size_t)D * 4, hipMemcpyDeviceToDevice, stream);
    hipMemcpyAsync(b01 + D, Bf[1], (size_t)D * 4, hipMemcpyDeviceToDevice, stream);
    for (int i = 0; i < 3; i++)
        hipMemcpyAsync(bstk + i * D, Bf[2 + i], (size_t)D * 4, hipMemcpyDeviceToDevice, stream);
    hipMemsetAsync(sums, 0, (size_t)(3 * NO + 2 * NR) * 4, stream);

    auto cast8 = [&](const float* in, unsigned char* out, long n, float sc) {
        long blocks = (n / 4 + 255) / 256; if (blocks > 4096) blocks = 4096;
        k_cast_fp8<<<dim3((unsigned)blocks), dim3(256), 0, stream>>>(in, out, n, sc);
    };
    cast8(Wf[0], W018,                 (long)D * D, 64.f);
    cast8(Wf[1], W018 + (size_t)D * D, (long)D * D, 64.f);
    for (int i = 0; i < 3; i++)
        cast8(Wf[2 + i], W2348 + (size_t)i * D * D, (long)D * D, 64.f);

    // fused single-pass prologue: fp8(16*attn) + transpose + exact sums
    k_prep16<true><<<dim3(NR / 64, NO / 64), dim3(256), 0, stream>>>(
        attn_sub, NR, Aobj8, Arel8, rsumS, csumS);
    k_prep16<true><<<dim3(NR / 64, NO / 64), dim3(256), 0, stream>>>(
        attn_obj, NR, Aobj8 + 16384, Arel8 + 2048, rsumS + NO, csumO);
    k_prep16<false><<<dim3(NO / 64, NO / 64), dim3(256), 0, stream>>>(
        attn_self, NO, Aobj8 + 32768, nullptr, rsumS + 2 * NO, nullptr);

    // derived per-row scales
    k_mkfin<<<dim3((3 * NO + 255) / 256), dim3(256), 0, stream>>>(
        rsumS, finS, 3 * NO, 3072.f);
    k_mkrel<<<dim3((NR + 255) / 256), dim3(256), 0, stream>>>(
        csumS, csumO, ratR, finR, NR);

    // initial fp8 snapshot of x_rel (later steps get it from dual's epilogue)
    cast8(x_rel, xrel8, (long)NR * D, 1.f);

    for (int step = 0; step < 2; ++step) {
        cast8(x_obj, xobj8, (long)NO * D, 1.f);

        // all 5 FC layers in ONE dispatch (fc01 + f234 roles)
        gemmf8mlp<<<dim3(1216), dim3(512), 0, stream>>>(
            W018, xrel8, W2348, xobj8, b01, bstk, fcObj8, fcRel8);

        // both collects in ONE dispatch (segment-aligned split-K)
        gemmf8_dual<<<dim3(1088), dim3(512), 0, stream>>>(
            Aobj8, fcObj8, x_obj, Arel8, fcRel8, x_rel, xrel8,
            finS, finO2, finSf, ratR, finR);
    }
}

// Round 18
// 773.506 us; speedup vs baseline: 1.8719x; 1.0682x over previous
//
#include <hip/hip_runtime.h>
#include <hip/hip_bf16.h>

typedef __attribute__((ext_vector_type(4))) float  f32x4;
typedef __attribute__((ext_vector_type(4))) int    i32x4;
typedef __attribute__((ext_vector_type(8))) int    i32x8;

// problem constants
#define NOBJ 2048
#define NREL 16384
#define DIM  1024
#define KOBJ 34816   /* 16384 + 16384 + 2048 */
#define KREL 4096    /* 2048 + 2048 */

#define AS1Q __attribute__((address_space(1)))
#define AS3Q __attribute__((address_space(3)))

__device__ __forceinline__ void gload_lds16(const void* g, void* l) {
    __builtin_amdgcn_global_load_lds((AS1Q void*)const_cast<void*>(g),
                                     (AS3Q void*)l, 16, 0, 0);
}

// all-ones (E8M0 = 127) block scales: plain fp8 matmul at MX rate
#define MFMA_F8(ACC, Af, Bf) \
    ACC = __builtin_amdgcn_mfma_scale_f32_16x16x128_f8f6f4( \
        Af, Bf, ACC, 0, 0, 0, 0x7F7F7F7F, 0, 0x7F7F7F7F)

__device__ __forceinline__ unsigned char fp8_byte(float x) {
    return (unsigned char)(__builtin_amdgcn_cvt_pk_fp8_f32(x, x, 0, false) & 0xFF);
}
__device__ __forceinline__ unsigned pk4_fp8(float a, float b, float c, float d) {
    int v = __builtin_amdgcn_cvt_pk_fp8_f32(a, b, 0, false);
    v = __builtin_amdgcn_cvt_pk_fp8_f32(c, d, v, true);
    return (unsigned)v;
}

// ---------------------------------------------------------------------------
// Merged MX-fp8 FC kernel (fc01 + f234 in one dispatch), occ structure:
// 128x256 tile, 48 KiB LDS, 512 thr (8 waves 2Mx4N, 64x64 out), K=1024, NT=8.
// Role by swizzled id s (1216 blocks):
//   s<1024: fc01  A=W01_8[2048][1024] (64*W), B=xrel8[16384][1024], bias=b01
//   else:   f234  A=W234_8[3072][1024] (64*W), B=xobj8[2048][1024], bias=bstk
// Epilogue value: fp8(relu(acc + 64*bias[m]))  (x64 convention, undone in dual)
// ---------------------------------------------------------------------------
__global__ __launch_bounds__(512, 4)
void gemmf8mlp(const unsigned char* __restrict__ W01, const unsigned char* __restrict__ xrel8,
               const unsigned char* __restrict__ W234, const unsigned char* __restrict__ xobj8,
               const float* __restrict__ b01, const float* __restrict__ bstk,
               unsigned char* __restrict__ fcObj8, unsigned char* __restrict__ fcRel8)
{
    __shared__ __align__(16) char lds[49152];

    const int tid  = threadIdx.x;
    const int lane = tid & 63;
    const int wid  = tid >> 6;
    const int wr = wid >> 2, wc = wid & 3;
    const int l15 = lane & 15, lk = lane >> 4;

    const int bid = blockIdx.x;                 // 1216, %8==0
    const int s   = (bid & 7) * 152 + (bid >> 3);

    const unsigned char* A; const unsigned char* B; const float* bias; bool isFC;
    long rowM0, rowN0;
    if (s < 1024) {
        rowM0 = (long)(s >> 6) * 128;
        rowN0 = (long)(s & 63) * 256;
        A = W01; B = xrel8; bias = b01; isFC = true;
    } else {
        const int t = s - 1024;
        rowM0 = (long)(t >> 3) * 128;
        rowN0 = (long)(t & 7) * 256;
        A = W234; B = xobj8; bias = bstk; isFC = false;
    }
    const long ld = DIM;
    const int  NT = DIM >> 7;           // 8

    const int rs = tid >> 3;
    const int kc = (tid & 7) ^ (rs & 7);
    const char* gA = (const char*)A + (rowM0 + rs) * ld + kc * 16;
    const char* gB = (const char*)B + (rowN0 + rs) * ld + kc * 16;
    char* lA = (char*)lds + tid * 16;
    char* lB = (char*)lds + 16384 + tid * 16;

    const int xc0 = ((2 * lk + 0) ^ (l15 & 7)) * 16;
    const int xc1 = ((2 * lk + 1) ^ (l15 & 7)) * 16;
    const int baseA = (wr * 64 + l15) * 128;
    const int baseB = 16384 + (wc * 64 + l15) * 128;

#define LDF8(dst, off) { \
    i32x4 lo_ = *(const i32x4*)((const char*)lds + (off) + xc0); \
    i32x4 hi_ = *(const i32x4*)((const char*)lds + (off) + xc1); \
    dst = __builtin_shufflevector(lo_, hi_, 0, 1, 2, 3, 4, 5, 6, 7); }

    f32x4 acc[4][4];
    #pragma unroll
    for (int i = 0; i < 4; i++)
        #pragma unroll
        for (int j = 0; j < 4; j++) acc[i][j] = f32x4{0.f, 0.f, 0.f, 0.f};

    for (int t = 0; t < NT; ++t) {
        const long kByte = (long)t * 128;
        gload_lds16(gA + kByte, lA);
        gload_lds16(gA + kByte + 64 * ld, lA + 8192);
        #pragma unroll
        for (int i = 0; i < 4; i++)
            gload_lds16(gB + kByte + (long)i * 64 * ld, lB + i * 8192);
        __syncthreads();

        i32x8 a[4];
        #pragma unroll
        for (int kf = 0; kf < 4; kf++) LDF8(a[kf], baseA + kf * 2048);
        #pragma unroll
        for (int j = 0; j < 4; j++) {
            i32x8 b;
            LDF8(b, baseB + j * 2048);
            #pragma unroll
            for (int kf = 0; kf < 4; kf++) MFMA_F8(acc[kf][j], a[kf], b);
        }
        __syncthreads();
    }
#undef LDF8

    #pragma unroll
    for (int kf = 0; kf < 4; kf++) {
        const long m0 = rowM0 + wr * 64 + kf * 16 + lk * 4;
        #pragma unroll
        for (int r = 0; r < 4; r++) {
            const long m = m0 + r;
            const float bs = 64.f * bias[m];
            #pragma unroll
            for (int j = 0; j < 4; j++) {
                const long n = rowN0 + wc * 64 + j * 16 + l15;
                const float v = fmaxf(acc[kf][j][r] + bs, 0.f);
                const unsigned char o = fp8_byte(v);
                if (isFC) {
                    fcObj8[(m & 1023) * (long)KOBJ + (m >> 10) * 16384 + n] = o;
                } else {
                    if (m < 1024)       fcRel8[m * (long)KREL + n] = o;
                    else if (m < 2048)  fcRel8[(m - 1024) * (long)KREL + 2048 + n] = o;
                    else                fcObj8[(m - 2048) * (long)KOBJ + 32768 + n] = o;
                }
            }
        }
    }
}

// ---------------------------------------------------------------------------
// Dual-role 128x256 MX-fp8 collect kernel (one dispatch = both collects).
// Scales pre-folded into the fp8 attn operands (R14 champion config).
// colRel epilogue additionally emits xrel8 = fp8(updated x_rel) for the next
// step's fc (single-writer, z=1).  Scales /64 undo the x64 fc convention.
// ---------------------------------------------------------------------------
__global__ __launch_bounds__(512, 4)
void gemmf8_dual(const unsigned char* __restrict__ Ao, const unsigned char* __restrict__ Bo,
                 float* __restrict__ Co,
                 const unsigned char* __restrict__ Ar, const unsigned char* __restrict__ Br,
                 float* __restrict__ Cr, unsigned char* __restrict__ xrel8out)
{
    __shared__ __align__(16) char lds[49152];   // A[128][128B] @0, B[256][128B] @16384

    const int tid  = threadIdx.x;
    const int lane = tid & 63;
    const int wid  = tid >> 6;
    const int wr = wid >> 2, wc = wid & 3;
    const int l15 = lane & 15, lk = lane >> 4;

    const int bid = blockIdx.x;                 // 1024, %8==0
    const int s   = (bid & 7) * 128 + (bid >> 3);

    const unsigned char* A; const unsigned char* B; float* C;
    int K, NT; long kb0; float scale; bool at;
    long rowM0, rowN0;
    if (s < 512) {          // colObj: x_obj += (Aobj @ fcObj^T) * 2^-19
        const int zz = s >> 6, t = s & 63;      // 8 z-slices x 64 tiles (16x4)
        rowM0 = (long)(t >> 2) * 128; rowN0 = (long)(t & 3) * 256;
        A = Ao; B = Bo; C = Co;
        K = KOBJ; NT = 34; kb0 = (long)34 * zz * 128;
        scale = 1.f / (8192.f * 64.f); at = true;
    } else {                // colRel: x_rel += (Arel @ fcRel^T) * 2^-17
        const int t = s - 512;                  // 512 tiles (128x4)
        rowM0 = (long)(t >> 2) * 128; rowN0 = (long)(t & 3) * 256;
        A = Ar; B = Br; C = Cr;
        K = KREL; NT = 32; kb0 = 0;
        scale = 1.f / (2048.f * 64.f); at = false;
    }
    const long ld = (long)K;            // bytes per row

    const int rs = tid >> 3;                    // 0..63
    const int kc = (tid & 7) ^ (rs & 7);
    const char* gA = (const char*)A + (rowM0 + rs) * ld + kb0 + kc * 16;
    const char* gB = (const char*)B + (rowN0 + rs) * ld + kb0 + kc * 16;
    char* lA = (char*)lds + tid * 16;
    char* lB = (char*)lds + 16384 + tid * 16;

    const int xc0 = ((2 * lk + 0) ^ (l15 & 7)) * 16;
    const int xc1 = ((2 * lk + 1) ^ (l15 & 7)) * 16;
    const int baseA = (wr * 64 + l15) * 128;            // + kf*2048
    const int baseB = 16384 + (wc * 64 + l15) * 128;    // + j*2048

#define LDF8(dst, off) { \
    i32x4 lo_ = *(const i32x4*)((const char*)lds + (off) + xc0); \
    i32x4 hi_ = *(const i32x4*)((const char*)lds + (off) + xc1); \
    dst = __builtin_shufflevector(lo_, hi_, 0, 1, 2, 3, 4, 5, 6, 7); }

    f32x4 acc[4][4];
    #pragma unroll
    for (int i = 0; i < 4; i++)
        #pragma unroll
        for (int j = 0; j < 4; j++) acc[i][j] = f32x4{0.f, 0.f, 0.f, 0.f};

    for (int t = 0; t < NT; ++t) {
        const long kByte = (long)t * 128;
        gload_lds16(gA + kByte, lA);
        gload_lds16(gA + kByte + 64 * ld, lA + 8192);
        #pragma unroll
        for (int i = 0; i < 4; i++)
            gload_lds16(gB + kByte + (long)i * 64 * ld, lB + i * 8192);
        __syncthreads();   // compiler drains vmcnt+lgkmcnt here

        i32x8 a[4];
        #pragma unroll
        for (int kf = 0; kf < 4; kf++) LDF8(a[kf], baseA + kf * 2048);
        #pragma unroll
        for (int j = 0; j < 4; j++) {
            i32x8 b;
            LDF8(b, baseB + j * 2048);
            #pragma unroll
            for (int kf = 0; kf < 4; kf++) MFMA_F8(acc[kf][j], a[kf], b);
        }
        __syncthreads();
    }
#undef LDF8

    #pragma unroll
    for (int kf = 0; kf < 4; kf++) {
        const long m0 = rowM0 + wr * 64 + kf * 16 + lk * 4;
        #pragma unroll
        for (int r = 0; r < 4; r++) {
            const long m = m0 + r;
            #pragma unroll
            for (int j = 0; j < 4; j++) {
                const long n = rowN0 + wc * 64 + j * 16 + l15;
                const float v = acc[kf][j][r] * scale;
                const long idx = m * (long)DIM + n;
                if (at) {
                    atomicAdd(&C[idx], v);
                } else {
                    const float nv = C[idx] + v;
                    C[idx] = nv;
                    xrel8out[idx] = fp8_byte(nv);
                }
            }
        }
    }
}

__global__ __launch_bounds__(256)
void k_cast_fp8(const float* __restrict__ in, unsigned char* __restrict__ out,
                long n, float scale)
{
    const long stride = (long)gridDim.x * blockDim.x;
    for (long i = (long)blockIdx.x * blockDim.x + threadIdx.x; i * 4 < n; i += stride) {
        f32x4 v = *reinterpret_cast<const f32x4*>(in + i * 4);
        *reinterpret_cast<unsigned*>(out + i * 4) =
            pk4_fp8(v[0] * scale, v[1] * scale, v[2] * scale, v[3] * scale);
    }
}

// Pass 1: row-sum (+ optional col-sum) partials of f32 attn via atomics.
template<bool COLS>
__global__ __launch_bounds__(256)
void k_sums(const float* __restrict__ in, int C,
            float* __restrict__ rowsum, float* __restrict__ colsum)
{
    __shared__ float cpart[16][64];
    __shared__ float rpart[64][17];
    const int tid = threadIdx.x;
    const int tx  = tid & 15;
    const int ty  = tid >> 4;
    const long c0 = (long)blockIdx.x * 64;
    const long r0 = (long)blockIdx.y * 64;

    float cs0 = 0.f, cs1 = 0.f, cs2 = 0.f, cs3 = 0.f;
    #pragma unroll
    for (int i = 0; i < 4; i++) {
        const int r = i * 16 + ty;
        const f32x4 v = *reinterpret_cast<const f32x4*>(&in[(r0 + r) * (long)C + c0 + tx * 4]);
        rpart[r][tx] = v[0] + v[1] + v[2] + v[3];
        cs0 += v[0]; cs1 += v[1]; cs2 += v[2]; cs3 += v[3];
    }
    if (COLS) {
        cpart[ty][tx * 4 + 0] = cs0;
        cpart[ty][tx * 4 + 1] = cs1;
        cpart[ty][tx * 4 + 2] = cs2;
        cpart[ty][tx * 4 + 3] = cs3;
    }
    __syncthreads();
    if (tid < 64) {
        float rs = 0.f;
        #pragma unroll
        for (int k = 0; k < 16; k++) rs += rpart[tid][k];
        atomicAdd(&rowsum[r0 + tid], rs);
        if (COLS) {
            float cs = 0.f;
            #pragma unroll
            for (int k = 0; k < 16; k++) cs += cpart[k][tid];
            atomicAdd(&colsum[c0 + tid], cs);
        }
    }
}

__global__ __launch_bounds__(256)
void k_invscale(float* __restrict__ s, int n, float c)
{
    const int i = blockIdx.x * 256 + threadIdx.x;
    if (i < n) s[i] = c / (s[i] + 1e-7f);
}

// Pass 2: fp8 operands in concat layouts (scales pre-folded incl 2^13 / 2^11).
template<bool TRANS>
__global__ __launch_bounds__(256)
void k_prep2f8(const float* __restrict__ in, int C,
               unsigned char* __restrict__ Aobj, unsigned char* __restrict__ Arel,
               const float* __restrict__ invRow, const float* __restrict__ invCol)
{
    __shared__ float tile[64][65];
    const int tid = threadIdx.x;
    const int tx  = tid & 15;
    const int ty  = tid >> 4;
    const long c0 = (long)blockIdx.x * 64;
    const long r0 = (long)blockIdx.y * 64;

    #pragma unroll
    for (int i = 0; i < 4; i++) {
        const int r = i * 16 + ty;
        const f32x4 v = *reinterpret_cast<const f32x4*>(&in[(r0 + r) * (long)C + c0 + tx * 4]);
        const float sc = invRow[r0 + r];
        *reinterpret_cast<unsigned*>(&Aobj[(r0 + r) * (long)KOBJ + c0 + tx * 4]) =
            pk4_fp8(v[0] * sc, v[1] * sc, v[2] * sc, v[3] * sc);
        if (TRANS) *reinterpret_cast<f32x4*>(&tile[r][tx * 4]) = v;
    }
    if (TRANS) {
        __syncthreads();
        const int rr = tid & 63;
        const int cg = tid >> 6;
        #pragma unroll
        for (int i = 0; i < 16; i++) {
            const int c = cg * 16 + i;
            const float sc = invCol[c0 + c];
            Arel[(c0 + c) * (long)KREL + r0 + rr] = fp8_byte(tile[rr][c] * sc);
        }
    }
}

extern "C" void kernel_launch(void* const* d_in, const int* in_sizes, int n_in,
                              void* d_out, int out_size, void* d_ws, size_t ws_size,
                              hipStream_t stream)
{
    if (n_in < 15) return;
    const float* obj_feats = (const float*)d_in[0];
    const float* rel_feats = (const float*)d_in[1];
    const float* attn_sub  = (const float*)d_in[2];
    const float* attn_obj  = (const float*)d_in[3];
    const float* attn_self = (const float*)d_in[4];
    const float* Wf[5] = { (const float*)d_in[5], (const float*)d_in[7],
                           (const float*)d_in[9], (const float*)d_in[11], (const float*)d_in[13] };
    const float* Bf[5] = { (const float*)d_in[6], (const float*)d_in[8],
                           (const float*)d_in[10], (const float*)d_in[12], (const float*)d_in[14] };

    const int NO = NOBJ, NR = NREL, D = DIM;

    char* w = (char*)d_ws;
    auto take = [&](size_t bytes) { char* p = w; w += bytes; return p; };
    unsigned char* Aobj8  = (unsigned char*)take((size_t)NO * KOBJ);   // [2048][34816] fp8
    unsigned char* Arel8  = (unsigned char*)take((size_t)NR * KREL);   // [16384][4096] fp8
    unsigned char* fcObj8 = (unsigned char*)take((size_t)D * KOBJ);    // [1024][34816] fp8
    unsigned char* fcRel8 = (unsigned char*)take((size_t)D * KREL);    // [1024][4096]  fp8
    unsigned char* xrel8  = (unsigned char*)take((size_t)NR * D);
    unsigned char* xobj8  = (unsigned char*)take((size_t)NO * D);
    unsigned char* W018   = (unsigned char*)take((size_t)2 * D * D);   // fp8 (64*W)
    unsigned char* W2348  = (unsigned char*)take((size_t)3 * D * D);   // fp8 (64*W)
    float*  b01     = (float*)take((size_t)2 * D * 4);
    float*  bstk    = (float*)take((size_t)3 * D * 4);
    float*  sums    = (float*)take((size_t)(3 * NO + 2 * NR) * 4);
    float* invS     = sums;            // 2^13 * (1/3)/(rowsum+eps)
    float* invO     = sums + NO;
    float* invSelf  = sums + 2 * NO;
    float* invTS    = sums + 3 * NO;   // 2^11 * 0.5/(colsum+eps)
    float* invTO    = sums + 3 * NO + NR;
    if ((size_t)(w - (char*)d_ws) > ws_size) return;   // ws too small: fail loudly

    float* x_obj = (float*)d_out;
    float* x_rel = x_obj + (size_t)NO * D;

    hipMemcpyAsync(x_obj, obj_feats, (size_t)NO * D * 4, hipMemcpyDeviceToDevice, stream);
    hipMemcpyAsync(x_rel, rel_feats, (size_t)NR * D * 4, hipMemcpyDeviceToDevice, stream);
    hipMemcpyAsync(b01,     Bf[0], (size_t)D * 4, hipMemcpyDeviceToDevice, stream);
    hipMemcpyAsync(b01 + D, Bf[1], (size_t)D * 4, hipMemcpyDeviceToDevice, stream);
    for (int i = 0; i < 3; i++)
        hipMemcpyAsync(bstk + i * D, Bf[2 + i], (size_t)D * 4, hipMemcpyDeviceToDevice, stream);
    hipMemsetAsync(sums, 0, (size_t)(3 * NO + 2 * NR) * 4, stream);

    auto cast8 = [&](const float* in, unsigned char* out, long n, float sc) {
        long blocks = (n / 4 + 255) / 256; if (blocks > 4096) blocks = 4096;
        k_cast_fp8<<<dim3((unsigned)blocks), dim3(256), 0, stream>>>(in, out, n, sc);
    };
    cast8(Wf[0], W018,                 (long)D * D, 64.f);
    cast8(Wf[1], W018 + (size_t)D * D, (long)D * D, 64.f);
    for (int i = 0; i < 3; i++)
        cast8(Wf[2 + i], W2348 + (size_t)i * D * D, (long)D * D, 64.f);

    // pass 1: exact f32 row/col sums
    k_sums<true><<<dim3(NR / 64, NO / 64), dim3(256), 0, stream>>>(attn_sub, NR, invS, invTS);
    k_sums<true><<<dim3(NR / 64, NO / 64), dim3(256), 0, stream>>>(attn_obj, NR, invO, invTO);
    k_sums<false><<<dim3(NO / 64, NO / 64), dim3(256), 0, stream>>>(attn_self, NO, invSelf, nullptr);
    // fold global power-of-2 into the fp8 quantization scale
    k_invscale<<<dim3((3 * NO + 255) / 256), dim3(256), 0, stream>>>(sums, 3 * NO, 8192.f / 3.f);
    k_invscale<<<dim3((2 * NR + 255) / 256), dim3(256), 0, stream>>>(sums + 3 * NO, 2 * NR, 1024.f);

    // pass 2: fp8 operands in concat layouts
    k_prep2f8<true><<<dim3(NR / 64, NO / 64), dim3(256), 0, stream>>>(
        attn_sub, NR, Aobj8, Arel8, invS, invTS);
    k_prep2f8<true><<<dim3(NR / 64, NO / 64), dim3(256), 0, stream>>>(
        attn_obj, NR, Aobj8 + 16384, Arel8 + 2048, invO, invTO);
    k_prep2f8<false><<<dim3(NO / 64, NO / 64), dim3(256), 0, stream>>>(
        attn_self, NO, Aobj8 + 32768, nullptr, invSelf, nullptr);

    // initial fp8 snapshot of x_rel (subsequent steps get it from dual's epilogue)
    cast8(x_rel, xrel8, (long)NR * D, 1.f);

    for (int step = 0; step < 2; ++step) {
        cast8(x_obj, xobj8, (long)NO * D, 1.f);

        // all 5 FC layers in ONE dispatch (fc01 + f234 roles)
        gemmf8mlp<<<dim3(1216), dim3(512), 0, stream>>>(
            W018, xrel8, W2348, xobj8, b01, bstk, fcObj8, fcRel8);

        // both collects in ONE dispatch; colRel also emits xrel8 for next step
        gemmf8_dual<<<dim3(1024), dim3(512), 0, stream>>>(
            Aobj8, fcObj8, x_obj, Arel8, fcRel8, x_rel, xrel8);
    }
}